// Round 1
// baseline (359.700 us; speedup 1.0000x reference)
//
#include <hip/hip_runtime.h>
#include <math.h>

#define BATCH 128
#define CIN 3
#define H 224
#define W 224
#define C1 16
#define HP 56
#define WP 56
#define C2 32
#define H2 28
#define W2 28

// ---------------------------------------------------------------------------
// conv1 (s2,p1) + stats + 2x2 pool(max,min), SINGLE PASS.
// R7: thread = ONE pooled cell (2x2 conv outputs) x 8 channels, row-streamed
// FMA order. acc file 64->32 VGPRs, live set ~50 regs; __launch_bounds__(256,8)
// pins VGPR<=64 for 8 waves/SIMD residency (was 84 VGPR -> 4 waves/SIMD).
// Grid (1568, 2) = 12544 waves (was 6272): 12.25 waves/SIMD of work.
// ---------------------------------------------------------------------------
__global__ __launch_bounds__(256, 8) void conv1_fused_k(
    const float* __restrict__ x, const float* __restrict__ w1,
    const float* __restrict__ b1, float2* __restrict__ mm,
    float* __restrict__ s_sum, float* __restrict__ s_sq)
{
    __shared__ float red[4][8], redq[4][8];
    const int tid = threadIdx.x;
    const int t = blockIdx.x * 256 + tid;   // 0..401407
    const int c0 = blockIdx.y * 8;
    const int n = t / 3136;                 // image
    const int r = t % 3136;
    const int ph = r / 56;                  // pooled row 0..55
    const int pw = r % 56;                  // pooled col 0..55
    const int rbase = 4 * ph - 1;           // first input row (conv rows 2ph,2ph+1)
    const int cbase = 4 * pw;
    const bool topok = ph > 0;
    const bool pwok  = pw > 0;

    float acc[8][4];                        // [channel][pooled-cell quadrant]
#pragma unroll
    for (int j = 0; j < 8; ++j) {
        const float bb = b1[c0 + j];
#pragma unroll
        for (int q = 0; q < 4; ++q) acc[j][q] = bb;
    }

#pragma unroll
    for (int ci = 0; ci < CIN; ++ci) {
        const float* img = x + (n * CIN + ci) * (H * W);
        // Row streaming: 5 input rows (rbase..rbase+4); row l feeds
        //   kh = l   (conv row 2ph,   quadrants 0,1) when l < 3
        //   kh = l-2 (conv row 2ph+1, quadrants 2,3) when l >= 2
#pragma unroll
        for (int l = 0; l < 5; ++l) {
            const int ih = max(rbase + l, 0);
            const float* rowp = img + ih * W;
            const float4 f4 = *(const float4*)(rowp + cbase);
            const float lf = rowp[max(cbase - 1, 0)];
            const bool rok = (l > 0) || topok;   // folds to true for l>0
            const float p0 = (rok && pwok) ? lf : 0.0f;
            const float p1 = rok ? f4.x : 0.0f;
            const float p2 = rok ? f4.y : 0.0f;
            const float p3 = rok ? f4.z : 0.0f;
            const float p4 = rok ? f4.w : 0.0f;
#pragma unroll
            for (int j = 0; j < 8; ++j) {
                const float* wc = w1 + ((c0 + j) * CIN + ci) * 9;  // uniform->SGPR
                if (l < 3) {
                    const float wa = wc[l * 3 + 0];
                    const float wb = wc[l * 3 + 1];
                    const float wd = wc[l * 3 + 2];
                    acc[j][0] += wa * p0 + wb * p1 + wd * p2;
                    acc[j][1] += wa * p2 + wb * p3 + wd * p4;
                }
                if (l >= 2) {
                    const int kh = l - 2;
                    const float wa = wc[kh * 3 + 0];
                    const float wb = wc[kh * 3 + 1];
                    const float wd = wc[kh * 3 + 2];
                    acc[j][2] += wa * p0 + wb * p1 + wd * p2;
                    acc[j][3] += wa * p2 + wb * p3 + wd * p4;
                }
            }
        }
    }

#pragma unroll
    for (int j = 0; j < 8; ++j) {
        const int o = (n * C1 + c0 + j) * (HP * WP) + ph * WP + pw;
        const float a0 = acc[j][0], a1 = acc[j][1], a2 = acc[j][2], a3 = acc[j][3];
        mm[o] = make_float2(fmaxf(fmaxf(a0, a1), fmaxf(a2, a3)),
                            fminf(fminf(a0, a1), fminf(a2, a3)));
        float s = a0 + a1 + a2 + a3;
        float q = a0 * a0 + a1 * a1 + a2 * a2 + a3 * a3;
#pragma unroll
        for (int off = 32; off > 0; off >>= 1) {
            s += __shfl_xor(s, off);
            q += __shfl_xor(q, off);
        }
        if ((tid & 63) == 0) { red[tid >> 6][j] = s; redq[tid >> 6][j] = q; }
    }
    __syncthreads();
    if (tid < 8) {
        atomicAdd(&s_sum[c0 + tid],
                  red[0][tid] + red[1][tid] + red[2][tid] + red[3][tid]);
    } else if (tid < 16) {
        const int j = tid - 8;
        atomicAdd(&s_sq[c0 + j],
                  redq[0][j] + redq[1][j] + redq[2][j] + redq[3][j]);
    }
}

// ---------------------------------------------------------------------------
// conv2 (s2,p1) + stats; BN1 finalize folded in (unchanged this round).
// Thread = ONE output position x 8 channels. Grid (392, 4).
// ---------------------------------------------------------------------------
__global__ __launch_bounds__(256) void conv2_k(
    const float2* __restrict__ mm,
    const float* __restrict__ s1sum, const float* __restrict__ s1sq,
    const float* __restrict__ g1, const float* __restrict__ be1,
    const float* __restrict__ w2, const float* __restrict__ b2,
    float* __restrict__ y2,
    float* __restrict__ s_sum, float* __restrict__ s_sq)
{
    __shared__ float red[4][8], redq[4][8];
    const int tid = threadIdx.x;
    const int t = blockIdx.x * 256 + tid;   // 0..100351
    const int c0 = blockIdx.y * 8;
    const int n = t / 784;
    const int p = t % 784;
    const int oh = p / W2, ow = p % W2;
    const bool topok = oh > 0;
    const bool owok  = ow > 0;
    const float inv1 = 1.0f / (float)(BATCH * 112 * 112);

    float acc[8];
#pragma unroll
    for (int c = 0; c < 8; ++c) acc[c] = b2[c0 + c];

#pragma unroll 2
    for (int ci = 0; ci < C1; ++ci) {
        const float mean = s1sum[ci] * inv1;
        const float var  = s1sq[ci] * inv1 - mean * mean;
        const float s1 = g1[ci] * rsqrtf(var + 1e-5f);
        const float t1 = be1[ci] - mean * s1;

        const float2* pl = mm + (n * C1 + ci) * (HP * WP);
        float v[3][3];
#pragma unroll
        for (int kh = 0; kh < 3; ++kh) {
            const int ih = max(2 * oh - 1 + kh, 0);
            const float2* rowp = pl + ih * WP;
            const float4 f4 = *(const float4*)(rowp + 2 * ow);
            const float2 lp = rowp[max(2 * ow - 1, 0)];
            const bool rok = (kh > 0) || topok;   // folds for kh>0
            const float h0 = fmaxf(0.0f, fmaxf(s1 * lp.x + t1, s1 * lp.y + t1));
            const float h1 = fmaxf(0.0f, fmaxf(s1 * f4.x + t1, s1 * f4.y + t1));
            const float h2 = fmaxf(0.0f, fmaxf(s1 * f4.z + t1, s1 * f4.w + t1));
            v[kh][0] = (rok && owok) ? h0 : 0.0f;
            v[kh][1] = rok ? h1 : 0.0f;
            v[kh][2] = rok ? h2 : 0.0f;
        }
#pragma unroll
        for (int c = 0; c < 8; ++c) {
            const float* wc = w2 + ((c0 + c) * C1 + ci) * 9;   // uniform
            float a = acc[c];
            a += wc[0] * v[0][0]; a += wc[1] * v[0][1]; a += wc[2] * v[0][2];
            a += wc[3] * v[1][0]; a += wc[4] * v[1][1]; a += wc[5] * v[1][2];
            a += wc[6] * v[2][0]; a += wc[7] * v[2][1]; a += wc[8] * v[2][2];
            acc[c] = a;
        }
    }

#pragma unroll
    for (int c = 0; c < 8; ++c) {
        const float a = acc[c];
        y2[(n * C2 + c0 + c) * (H2 * W2) + p] = a;
        float s = a, q = a * a;
#pragma unroll
        for (int off = 32; off > 0; off >>= 1) {
            s += __shfl_xor(s, off);
            q += __shfl_xor(q, off);
        }
        if ((tid & 63) == 0) { red[tid >> 6][c] = s; redq[tid >> 6][c] = q; }
    }
    __syncthreads();
    if (tid < 8) {
        atomicAdd(&s_sum[c0 + tid],
                  red[0][tid] + red[1][tid] + red[2][tid] + red[3][tid]);
    } else if (tid < 16) {
        const int c = tid - 8;
        atomicAdd(&s_sq[c0 + c],
                  redq[0][c] + redq[1][c] + redq[2][c] + redq[3][c]);
    }
}

// ---------------------------------------------------------------------------
// head fused: BN2 finalize + ReLU + avgpool + FC + cos, one block per image.
// ---------------------------------------------------------------------------
__global__ __launch_bounds__(256) void head_fused_k(
    const float* __restrict__ y2,
    const float* __restrict__ s2sum, const float* __restrict__ s2sq,
    const float* __restrict__ g2, const float* __restrict__ be2,
    const float* __restrict__ fcw, const float* __restrict__ fcb,
    float* __restrict__ out)
{
    __shared__ float feat[C2];
    const int n = blockIdx.x;
    const int tid = threadIdx.x;
    const int wave = tid >> 6, lane = tid & 63;
    const float inv2 = 1.0f / (float)(BATCH * H2 * W2);
#pragma unroll
    for (int k = 0; k < 8; ++k) {
        const int c = wave * 8 + k;
        const float mean = s2sum[c] * inv2;
        const float var  = s2sq[c] * inv2 - mean * mean;
        const float s = g2[c] * rsqrtf(var + 1e-5f);
        const float t = be2[c] - mean * s;
        const float4* yp = (const float4*)(y2 + (n * C2 + c) * (H2 * W2));
        float a = 0.0f;
        for (int i = lane; i < 196; i += 64) {       // 196 quads = 784
            const float4 v = yp[i];
            a += fmaxf(0.0f, s * v.x + t) + fmaxf(0.0f, s * v.y + t)
               + fmaxf(0.0f, s * v.z + t) + fmaxf(0.0f, s * v.w + t);
        }
#pragma unroll
        for (int off = 32; off > 0; off >>= 1) a += __shfl_xor(a, off);
        if (lane == 0) feat[c] = a * (1.0f / (H2 * W2));
    }
    __syncthreads();
    if (tid == 0) {
        float logit = fcb[0];
#pragma unroll
        for (int c = 0; c < C2; ++c) logit += feat[c] * fcw[c];
        const float pc = cosf(logit);
        out[2 * n]     = pc;
        out[2 * n + 1] = 1.0f - pc;
    }
}

extern "C" void kernel_launch(void* const* d_in, const int* in_sizes, int n_in,
                              void* d_out, int out_size, void* d_ws, size_t ws_size,
                              hipStream_t stream) {
    const float* x   = (const float*)d_in[0];
    const float* w1  = (const float*)d_in[1];
    const float* b1  = (const float*)d_in[2];
    const float* g1  = (const float*)d_in[3];
    const float* be1 = (const float*)d_in[4];
    const float* w2  = (const float*)d_in[5];
    const float* b2  = (const float*)d_in[6];
    const float* g2  = (const float*)d_in[7];
    const float* be2 = (const float*)d_in[8];
    const float* fcw = (const float*)d_in[9];
    const float* fcb = (const float*)d_in[10];
    float* out = (float*)d_out;

    float* ws = (float*)d_ws;
    float2* mm = (float2*)ws;                              // 6,422,528 float2
    float* y2 = ws + (size_t)2 * BATCH * C1 * HP * WP;     // 3,211,264 floats
    float* stats = y2 + (size_t)BATCH * C2 * H2 * W2;
    float* s1sum = stats;          // 16
    float* s1sq  = stats + 16;     // 16
    float* s2sum = stats + 32;     // 32
    float* s2sq  = stats + 64;     // 32
    // ws use ~64.3 MB (proven safe)

    hipMemsetAsync(stats, 0, 96 * sizeof(float), stream);

    conv1_fused_k<<<dim3(1568, 2), 256, 0, stream>>>(x, w1, b1, mm, s1sum, s1sq);
    conv2_k<<<dim3(392, 4), 256, 0, stream>>>(mm, s1sum, s1sq, g1, be1,
                                              w2, b2, y2, s2sum, s2sq);
    head_fused_k<<<BATCH, 256, 0, stream>>>(y2, s2sum, s2sq, g2, be2,
                                            fcw, fcb, out);
}

// Round 2
// 235.114 us; speedup vs baseline: 1.5299x; 1.5299x over previous
//
#include <hip/hip_runtime.h>
#include <math.h>

#define BATCH 128
#define CIN 3
#define H 224
#define W 224
#define C1 16
#define HP 56
#define WP 56
#define C2 32
#define H2 28
#define W2 28

// ---------------------------------------------------------------------------
// conv1 (s2,p1) + stats + 2x2 pool(max,min), SINGLE PASS.
// R8: R7's row-streamed one-cell structure (30 loads/thread, 32-reg acc,
// correctness-proven) but WITHOUT the min-waves launch bound. R7's
// __launch_bounds__(256,8) drove the allocator to 32 VGPR and spilled the
// accumulators (FETCH 85->426MB, WRITE 50->215MB = scratch traffic).
// Natural demand ~50-60 VGPR should land under the 64-VGPR occupancy cliff
// (m69: waves/CU halves at 64/128/256) without forcing.
// Grid (1568, 2) = 12544 waves: 12.25 waves/SIMD of work.
// ---------------------------------------------------------------------------
__global__ __launch_bounds__(256) void conv1_fused_k(
    const float* __restrict__ x, const float* __restrict__ w1,
    const float* __restrict__ b1, float2* __restrict__ mm,
    float* __restrict__ s_sum, float* __restrict__ s_sq)
{
    __shared__ float red[4][8], redq[4][8];
    const int tid = threadIdx.x;
    const int t = blockIdx.x * 256 + tid;   // 0..401407
    const int c0 = blockIdx.y * 8;
    const int n = t / 3136;                 // image
    const int r = t % 3136;
    const int ph = r / 56;                  // pooled row 0..55
    const int pw = r % 56;                  // pooled col 0..55
    const int rbase = 4 * ph - 1;           // first input row (conv rows 2ph,2ph+1)
    const int cbase = 4 * pw;
    const bool topok = ph > 0;
    const bool pwok  = pw > 0;

    float acc[8][4];                        // [channel][pooled-cell quadrant]
#pragma unroll
    for (int j = 0; j < 8; ++j) {
        const float bb = b1[c0 + j];
#pragma unroll
        for (int q = 0; q < 4; ++q) acc[j][q] = bb;
    }

#pragma unroll
    for (int ci = 0; ci < CIN; ++ci) {
        const float* img = x + (n * CIN + ci) * (H * W);
        // Row streaming: 5 input rows (rbase..rbase+4); row l feeds
        //   kh = l   (conv row 2ph,   quadrants 0,1) when l < 3
        //   kh = l-2 (conv row 2ph+1, quadrants 2,3) when l >= 2
#pragma unroll
        for (int l = 0; l < 5; ++l) {
            const int ih = max(rbase + l, 0);
            const float* rowp = img + ih * W;
            const float4 f4 = *(const float4*)(rowp + cbase);
            const float lf = rowp[max(cbase - 1, 0)];
            const bool rok = (l > 0) || topok;   // folds to true for l>0
            const float p0 = (rok && pwok) ? lf : 0.0f;
            const float p1 = rok ? f4.x : 0.0f;
            const float p2 = rok ? f4.y : 0.0f;
            const float p3 = rok ? f4.z : 0.0f;
            const float p4 = rok ? f4.w : 0.0f;
#pragma unroll
            for (int j = 0; j < 8; ++j) {
                const float* wc = w1 + ((c0 + j) * CIN + ci) * 9;  // uniform->SGPR
                if (l < 3) {
                    const float wa = wc[l * 3 + 0];
                    const float wb = wc[l * 3 + 1];
                    const float wd = wc[l * 3 + 2];
                    acc[j][0] += wa * p0 + wb * p1 + wd * p2;
                    acc[j][1] += wa * p2 + wb * p3 + wd * p4;
                }
                if (l >= 2) {
                    const int kh = l - 2;
                    const float wa = wc[kh * 3 + 0];
                    const float wb = wc[kh * 3 + 1];
                    const float wd = wc[kh * 3 + 2];
                    acc[j][2] += wa * p0 + wb * p1 + wd * p2;
                    acc[j][3] += wa * p2 + wb * p3 + wd * p4;
                }
            }
        }
    }

#pragma unroll
    for (int j = 0; j < 8; ++j) {
        const int o = (n * C1 + c0 + j) * (HP * WP) + ph * WP + pw;
        const float a0 = acc[j][0], a1 = acc[j][1], a2 = acc[j][2], a3 = acc[j][3];
        mm[o] = make_float2(fmaxf(fmaxf(a0, a1), fmaxf(a2, a3)),
                            fminf(fminf(a0, a1), fminf(a2, a3)));
        float s = a0 + a1 + a2 + a3;
        float q = a0 * a0 + a1 * a1 + a2 * a2 + a3 * a3;
#pragma unroll
        for (int off = 32; off > 0; off >>= 1) {
            s += __shfl_xor(s, off);
            q += __shfl_xor(q, off);
        }
        if ((tid & 63) == 0) { red[tid >> 6][j] = s; redq[tid >> 6][j] = q; }
    }
    __syncthreads();
    if (tid < 8) {
        atomicAdd(&s_sum[c0 + tid],
                  red[0][tid] + red[1][tid] + red[2][tid] + red[3][tid]);
    } else if (tid < 16) {
        const int j = tid - 8;
        atomicAdd(&s_sq[c0 + j],
                  redq[0][j] + redq[1][j] + redq[2][j] + redq[3][j]);
    }
}

// ---------------------------------------------------------------------------
// conv2 (s2,p1) + stats; BN1 finalize folded in (unchanged this round).
// Thread = ONE output position x 8 channels. Grid (392, 4).
// ---------------------------------------------------------------------------
__global__ __launch_bounds__(256) void conv2_k(
    const float2* __restrict__ mm,
    const float* __restrict__ s1sum, const float* __restrict__ s1sq,
    const float* __restrict__ g1, const float* __restrict__ be1,
    const float* __restrict__ w2, const float* __restrict__ b2,
    float* __restrict__ y2,
    float* __restrict__ s_sum, float* __restrict__ s_sq)
{
    __shared__ float red[4][8], redq[4][8];
    const int tid = threadIdx.x;
    const int t = blockIdx.x * 256 + tid;   // 0..100351
    const int c0 = blockIdx.y * 8;
    const int n = t / 784;
    const int p = t % 784;
    const int oh = p / W2, ow = p % W2;
    const bool topok = oh > 0;
    const bool owok  = ow > 0;
    const float inv1 = 1.0f / (float)(BATCH * 112 * 112);

    float acc[8];
#pragma unroll
    for (int c = 0; c < 8; ++c) acc[c] = b2[c0 + c];

#pragma unroll 2
    for (int ci = 0; ci < C1; ++ci) {
        const float mean = s1sum[ci] * inv1;
        const float var  = s1sq[ci] * inv1 - mean * mean;
        const float s1 = g1[ci] * rsqrtf(var + 1e-5f);
        const float t1 = be1[ci] - mean * s1;

        const float2* pl = mm + (n * C1 + ci) * (HP * WP);
        float v[3][3];
#pragma unroll
        for (int kh = 0; kh < 3; ++kh) {
            const int ih = max(2 * oh - 1 + kh, 0);
            const float2* rowp = pl + ih * WP;
            const float4 f4 = *(const float4*)(rowp + 2 * ow);
            const float2 lp = rowp[max(2 * ow - 1, 0)];
            const bool rok = (kh > 0) || topok;   // folds for kh>0
            const float h0 = fmaxf(0.0f, fmaxf(s1 * lp.x + t1, s1 * lp.y + t1));
            const float h1 = fmaxf(0.0f, fmaxf(s1 * f4.x + t1, s1 * f4.y + t1));
            const float h2 = fmaxf(0.0f, fmaxf(s1 * f4.z + t1, s1 * f4.w + t1));
            v[kh][0] = (rok && owok) ? h0 : 0.0f;
            v[kh][1] = rok ? h1 : 0.0f;
            v[kh][2] = rok ? h2 : 0.0f;
        }
#pragma unroll
        for (int c = 0; c < 8; ++c) {
            const float* wc = w2 + ((c0 + c) * C1 + ci) * 9;   // uniform
            float a = acc[c];
            a += wc[0] * v[0][0]; a += wc[1] * v[0][1]; a += wc[2] * v[0][2];
            a += wc[3] * v[1][0]; a += wc[4] * v[1][1]; a += wc[5] * v[1][2];
            a += wc[6] * v[2][0]; a += wc[7] * v[2][1]; a += wc[8] * v[2][2];
            acc[c] = a;
        }
    }

#pragma unroll
    for (int c = 0; c < 8; ++c) {
        const float a = acc[c];
        y2[(n * C2 + c0 + c) * (H2 * W2) + p] = a;
        float s = a, q = a * a;
#pragma unroll
        for (int off = 32; off > 0; off >>= 1) {
            s += __shfl_xor(s, off);
            q += __shfl_xor(q, off);
        }
        if ((tid & 63) == 0) { red[tid >> 6][c] = s; redq[tid >> 6][c] = q; }
    }
    __syncthreads();
    if (tid < 8) {
        atomicAdd(&s_sum[c0 + tid],
                  red[0][tid] + red[1][tid] + red[2][tid] + red[3][tid]);
    } else if (tid < 16) {
        const int c = tid - 8;
        atomicAdd(&s_sq[c0 + c],
                  redq[0][c] + redq[1][c] + redq[2][c] + redq[3][c]);
    }
}

// ---------------------------------------------------------------------------
// head fused: BN2 finalize + ReLU + avgpool + FC + cos, one block per image.
// ---------------------------------------------------------------------------
__global__ __launch_bounds__(256) void head_fused_k(
    const float* __restrict__ y2,
    const float* __restrict__ s2sum, const float* __restrict__ s2sq,
    const float* __restrict__ g2, const float* __restrict__ be2,
    const float* __restrict__ fcw, const float* __restrict__ fcb,
    float* __restrict__ out)
{
    __shared__ float feat[C2];
    const int n = blockIdx.x;
    const int tid = threadIdx.x;
    const int wave = tid >> 6, lane = tid & 63;
    const float inv2 = 1.0f / (float)(BATCH * H2 * W2);
#pragma unroll
    for (int k = 0; k < 8; ++k) {
        const int c = wave * 8 + k;
        const float mean = s2sum[c] * inv2;
        const float var  = s2sq[c] * inv2 - mean * mean;
        const float s = g2[c] * rsqrtf(var + 1e-5f);
        const float t = be2[c] - mean * s;
        const float4* yp = (const float4*)(y2 + (n * C2 + c) * (H2 * W2));
        float a = 0.0f;
        for (int i = lane; i < 196; i += 64) {       // 196 quads = 784
            const float4 v = yp[i];
            a += fmaxf(0.0f, s * v.x + t) + fmaxf(0.0f, s * v.y + t)
               + fmaxf(0.0f, s * v.z + t) + fmaxf(0.0f, s * v.w + t);
        }
#pragma unroll
        for (int off = 32; off > 0; off >>= 1) a += __shfl_xor(a, off);
        if (lane == 0) feat[c] = a * (1.0f / (H2 * W2));
    }
    __syncthreads();
    if (tid == 0) {
        float logit = fcb[0];
#pragma unroll
        for (int c = 0; c < C2; ++c) logit += feat[c] * fcw[c];
        const float pc = cosf(logit);
        out[2 * n]     = pc;
        out[2 * n + 1] = 1.0f - pc;
    }
}

extern "C" void kernel_launch(void* const* d_in, const int* in_sizes, int n_in,
                              void* d_out, int out_size, void* d_ws, size_t ws_size,
                              hipStream_t stream) {
    const float* x   = (const float*)d_in[0];
    const float* w1  = (const float*)d_in[1];
    const float* b1  = (const float*)d_in[2];
    const float* g1  = (const float*)d_in[3];
    const float* be1 = (const float*)d_in[4];
    const float* w2  = (const float*)d_in[5];
    const float* b2  = (const float*)d_in[6];
    const float* g2  = (const float*)d_in[7];
    const float* be2 = (const float*)d_in[8];
    const float* fcw = (const float*)d_in[9];
    const float* fcb = (const float*)d_in[10];
    float* out = (float*)d_out;

    float* ws = (float*)d_ws;
    float2* mm = (float2*)ws;                              // 6,422,528 float2
    float* y2 = ws + (size_t)2 * BATCH * C1 * HP * WP;     // 3,211,264 floats
    float* stats = y2 + (size_t)BATCH * C2 * H2 * W2;
    float* s1sum = stats;          // 16
    float* s1sq  = stats + 16;     // 16
    float* s2sum = stats + 32;     // 32
    float* s2sq  = stats + 64;     // 32
    // ws use ~64.3 MB (proven safe)

    hipMemsetAsync(stats, 0, 96 * sizeof(float), stream);

    conv1_fused_k<<<dim3(1568, 2), 256, 0, stream>>>(x, w1, b1, mm, s1sum, s1sq);
    conv2_k<<<dim3(392, 4), 256, 0, stream>>>(mm, s1sum, s1sq, g1, be1,
                                              w2, b2, y2, s2sum, s2sq);
    head_fused_k<<<BATCH, 256, 0, stream>>>(y2, s2sum, s2sq, g2, be2,
                                            fcw, fcb, out);
}

// Round 4
// 230.701 us; speedup vs baseline: 1.5592x; 1.0191x over previous
//
#include <hip/hip_runtime.h>
#include <math.h>

#define BATCH 128
#define CIN 3
#define H 224
#define W 224
#define C1 16
#define HP 56
#define WP 56
#define C2 32
#define H2 28
#define W2 28

// ---------------------------------------------------------------------------
// conv1 (s2,p1) + stats + 2x2 pool(max,min), SINGLE PASS.
// R8-proven: row-streamed one-cell, VGPR=52 (8 waves/SIMD bucket), no spills,
// 69.6 us @ ~77% clock session. UNCHANGED (control dispatch).
// ---------------------------------------------------------------------------
__global__ __launch_bounds__(256) void conv1_fused_k(
    const float* __restrict__ x, const float* __restrict__ w1,
    const float* __restrict__ b1, float2* __restrict__ mm,
    float* __restrict__ s_sum, float* __restrict__ s_sq)
{
    __shared__ float red[4][8], redq[4][8];
    const int tid = threadIdx.x;
    const int t = blockIdx.x * 256 + tid;   // 0..401407
    const int c0 = blockIdx.y * 8;
    const int n = t / 3136;                 // image
    const int r = t % 3136;
    const int ph = r / 56;                  // pooled row 0..55
    const int pw = r % 56;                  // pooled col 0..55
    const int rbase = 4 * ph - 1;           // first input row (conv rows 2ph,2ph+1)
    const int cbase = 4 * pw;
    const bool topok = ph > 0;
    const bool pwok  = pw > 0;

    float acc[8][4];                        // [channel][pooled-cell quadrant]
#pragma unroll
    for (int j = 0; j < 8; ++j) {
        const float bb = b1[c0 + j];
#pragma unroll
        for (int q = 0; q < 4; ++q) acc[j][q] = bb;
    }

#pragma unroll
    for (int ci = 0; ci < CIN; ++ci) {
        const float* img = x + (n * CIN + ci) * (H * W);
        // Row streaming: 5 input rows (rbase..rbase+4); row l feeds
        //   kh = l   (conv row 2ph,   quadrants 0,1) when l < 3
        //   kh = l-2 (conv row 2ph+1, quadrants 2,3) when l >= 2
#pragma unroll
        for (int l = 0; l < 5; ++l) {
            const int ih = max(rbase + l, 0);
            const float* rowp = img + ih * W;
            const float4 f4 = *(const float4*)(rowp + cbase);
            const float lf = rowp[max(cbase - 1, 0)];
            const bool rok = (l > 0) || topok;   // folds to true for l>0
            const float p0 = (rok && pwok) ? lf : 0.0f;
            const float p1 = rok ? f4.x : 0.0f;
            const float p2 = rok ? f4.y : 0.0f;
            const float p3 = rok ? f4.z : 0.0f;
            const float p4 = rok ? f4.w : 0.0f;
#pragma unroll
            for (int j = 0; j < 8; ++j) {
                const float* wc = w1 + ((c0 + j) * CIN + ci) * 9;  // uniform->SGPR
                if (l < 3) {
                    const float wa = wc[l * 3 + 0];
                    const float wb = wc[l * 3 + 1];
                    const float wd = wc[l * 3 + 2];
                    acc[j][0] += wa * p0 + wb * p1 + wd * p2;
                    acc[j][1] += wa * p2 + wb * p3 + wd * p4;
                }
                if (l >= 2) {
                    const int kh = l - 2;
                    const float wa = wc[kh * 3 + 0];
                    const float wb = wc[kh * 3 + 1];
                    const float wd = wc[kh * 3 + 2];
                    acc[j][2] += wa * p0 + wb * p1 + wd * p2;
                    acc[j][3] += wa * p2 + wb * p3 + wd * p4;
                }
            }
        }
    }

#pragma unroll
    for (int j = 0; j < 8; ++j) {
        const int o = (n * C1 + c0 + j) * (HP * WP) + ph * WP + pw;
        const float a0 = acc[j][0], a1 = acc[j][1], a2 = acc[j][2], a3 = acc[j][3];
        mm[o] = make_float2(fmaxf(fmaxf(a0, a1), fmaxf(a2, a3)),
                            fminf(fminf(a0, a1), fminf(a2, a3)));
        float s = a0 + a1 + a2 + a3;
        float q = a0 * a0 + a1 * a1 + a2 * a2 + a3 * a3;
#pragma unroll
        for (int off = 32; off > 0; off >>= 1) {
            s += __shfl_xor(s, off);
            q += __shfl_xor(q, off);
        }
        if ((tid & 63) == 0) { red[tid >> 6][j] = s; redq[tid >> 6][j] = q; }
    }
    __syncthreads();
    if (tid < 8) {
        atomicAdd(&s_sum[c0 + tid],
                  red[0][tid] + red[1][tid] + red[2][tid] + red[3][tid]);
    } else if (tid < 16) {
        const int j = tid - 8;
        atomicAdd(&s_sq[c0 + j],
                  redq[0][j] + redq[1][j] + redq[2][j] + redq[3][j]);
    }
}

// ---------------------------------------------------------------------------
// conv2 (s2,p1) + stats; BN1 finalize folded in.
// R9: thread = TWO horizontally-adjacent outputs (ow, ow+1) x 8 channels.
// The pair shares input units 2ow-1..2ow+3: 9 loads per ci for 2 outputs
// (72/output vs 96/output before, -25%), h computed once per unit, loads
// batched 3-rows-at-a-time for MLP, y2 store is one float2.
// Grid (196, 4) = 3136 waves = 3.06 waves/SIMD: fits one residency
// generation even if VGPR lands in the 65-128 bucket (4 waves/SIMD).
// ---------------------------------------------------------------------------
__global__ __launch_bounds__(256) void conv2_k(
    const float2* __restrict__ mm,
    const float* __restrict__ s1sum, const float* __restrict__ s1sq,
    const float* __restrict__ g1, const float* __restrict__ be1,
    const float* __restrict__ w2, const float* __restrict__ b2,
    float* __restrict__ y2,
    float* __restrict__ s_sum, float* __restrict__ s_sq)
{
    __shared__ float red[4][8], redq[4][8];
    const int tid = threadIdx.x;
    const int t = blockIdx.x * 256 + tid;   // 0..50175
    const int c0 = blockIdx.y * 8;
    const int n = t / 392;                  // image
    const int r = t % 392;                  // 28 rows x 14 col-pairs
    const int oh = r / 14;
    const int ow = (r % 14) * 2;            // even; outputs ow, ow+1
    const bool topok = oh > 0;
    const bool owok  = ow > 0;
    const float inv1 = 1.0f / (float)(BATCH * 112 * 112);

    float accA[8], accB[8];
#pragma unroll
    for (int c = 0; c < 8; ++c) { accA[c] = b2[c0 + c]; accB[c] = accA[c]; }

#pragma unroll 2
    for (int ci = 0; ci < C1; ++ci) {
        const float mean = s1sum[ci] * inv1;
        const float var  = s1sq[ci] * inv1 - mean * mean;
        const float s1 = g1[ci] * rsqrtf(var + 1e-5f);
        const float t1 = be1[ci] - mean * s1;

        const float2* pl = mm + (n * C1 + ci) * (HP * WP);

        // batch all 9 loads (3 rows x {left float2, two float4}) first
        float4 fa[3], fb[3];
        float2 lpv[3];
#pragma unroll
        for (int kh = 0; kh < 3; ++kh) {
            const int ih = max(2 * oh - 1 + kh, 0);
            const float2* rowp = pl + ih * WP;
            fa[kh]  = *(const float4*)(rowp + 2 * ow);       // units 2ow,2ow+1
            fb[kh]  = *(const float4*)(rowp + 2 * ow + 2);   // units 2ow+2,2ow+3
            lpv[kh] = rowp[max(2 * ow - 1, 0)];              // unit 2ow-1
        }

        // BN1+ReLU+maxpool-sign-correct per unit: h = max(0, max(s*mx+t, s*mn+t))
        float h[3][5];
#pragma unroll
        for (int kh = 0; kh < 3; ++kh) {
            const bool rok = (kh > 0) || topok;   // folds for kh>0
            const float u0 = fmaxf(0.0f, fmaxf(s1 * lpv[kh].x + t1, s1 * lpv[kh].y + t1));
            const float u1 = fmaxf(0.0f, fmaxf(s1 * fa[kh].x + t1, s1 * fa[kh].y + t1));
            const float u2 = fmaxf(0.0f, fmaxf(s1 * fa[kh].z + t1, s1 * fa[kh].w + t1));
            const float u3 = fmaxf(0.0f, fmaxf(s1 * fb[kh].x + t1, s1 * fb[kh].y + t1));
            const float u4 = fmaxf(0.0f, fmaxf(s1 * fb[kh].z + t1, s1 * fb[kh].w + t1));
            h[kh][0] = (rok && owok) ? u0 : 0.0f;
            h[kh][1] = rok ? u1 : 0.0f;
            h[kh][2] = rok ? u2 : 0.0f;
            h[kh][3] = rok ? u3 : 0.0f;
            h[kh][4] = rok ? u4 : 0.0f;
        }

#pragma unroll
        for (int c = 0; c < 8; ++c) {
            const float* wc = w2 + ((c0 + c) * C1 + ci) * 9;   // uniform
            float a = accA[c], b = accB[c];
#pragma unroll
            for (int kh = 0; kh < 3; ++kh) {
                const float w0 = wc[kh * 3 + 0];
                const float w1v = wc[kh * 3 + 1];
                const float w2v = wc[kh * 3 + 2];
                a += w0 * h[kh][0] + w1v * h[kh][1] + w2v * h[kh][2];
                b += w0 * h[kh][2] + w1v * h[kh][3] + w2v * h[kh][4];
            }
            accA[c] = a; accB[c] = b;
        }
    }

#pragma unroll
    for (int c = 0; c < 8; ++c) {
        const float aA = accA[c], aB = accB[c];
        const int p = oh * W2 + ow;                       // even
        *(float2*)(y2 + (n * C2 + c0 + c) * (H2 * W2) + p) = make_float2(aA, aB);
        float s = aA + aB, q = aA * aA + aB * aB;
#pragma unroll
        for (int off = 32; off > 0; off >>= 1) {
            s += __shfl_xor(s, off);
            q += __shfl_xor(q, off);
        }
        if ((tid & 63) == 0) { red[tid >> 6][c] = s; redq[tid >> 6][c] = q; }
    }
    __syncthreads();
    if (tid < 8) {
        atomicAdd(&s_sum[c0 + tid],
                  red[0][tid] + red[1][tid] + red[2][tid] + red[3][tid]);
    } else if (tid < 16) {
        const int c = tid - 8;
        atomicAdd(&s_sq[c0 + c],
                  redq[0][c] + redq[1][c] + redq[2][c] + redq[3][c]);
    }
}

// ---------------------------------------------------------------------------
// head fused: BN2 finalize + ReLU + avgpool + FC + cos, one block per image.
// ---------------------------------------------------------------------------
__global__ __launch_bounds__(256) void head_fused_k(
    const float* __restrict__ y2,
    const float* __restrict__ s2sum, const float* __restrict__ s2sq,
    const float* __restrict__ g2, const float* __restrict__ be2,
    const float* __restrict__ fcw, const float* __restrict__ fcb,
    float* __restrict__ out)
{
    __shared__ float feat[C2];
    const int n = blockIdx.x;
    const int tid = threadIdx.x;
    const int wave = tid >> 6, lane = tid & 63;
    const float inv2 = 1.0f / (float)(BATCH * H2 * W2);
#pragma unroll
    for (int k = 0; k < 8; ++k) {
        const int c = wave * 8 + k;
        const float mean = s2sum[c] * inv2;
        const float var  = s2sq[c] * inv2 - mean * mean;
        const float s = g2[c] * rsqrtf(var + 1e-5f);
        const float t = be2[c] - mean * s;
        const float4* yp = (const float4*)(y2 + (n * C2 + c) * (H2 * W2));
        float a = 0.0f;
        for (int i = lane; i < 196; i += 64) {       // 196 quads = 784
            const float4 v = yp[i];
            a += fmaxf(0.0f, s * v.x + t) + fmaxf(0.0f, s * v.y + t)
               + fmaxf(0.0f, s * v.z + t) + fmaxf(0.0f, s * v.w + t);
        }
#pragma unroll
        for (int off = 32; off > 0; off >>= 1) a += __shfl_xor(a, off);
        if (lane == 0) feat[c] = a * (1.0f / (H2 * W2));
    }
    __syncthreads();
    if (tid == 0) {
        float logit = fcb[0];
#pragma unroll
        for (int c = 0; c < C2; ++c) logit += feat[c] * fcw[c];
        const float pc = cosf(logit);
        out[2 * n]     = pc;
        out[2 * n + 1] = 1.0f - pc;
    }
}

extern "C" void kernel_launch(void* const* d_in, const int* in_sizes, int n_in,
                              void* d_out, int out_size, void* d_ws, size_t ws_size,
                              hipStream_t stream) {
    const float* x   = (const float*)d_in[0];
    const float* w1  = (const float*)d_in[1];
    const float* b1  = (const float*)d_in[2];
    const float* g1  = (const float*)d_in[3];
    const float* be1 = (const float*)d_in[4];
    const float* w2  = (const float*)d_in[5];
    const float* b2  = (const float*)d_in[6];
    const float* g2  = (const float*)d_in[7];
    const float* be2 = (const float*)d_in[8];
    const float* fcw = (const float*)d_in[9];
    const float* fcb = (const float*)d_in[10];
    float* out = (float*)d_out;

    float* ws = (float*)d_ws;
    float2* mm = (float2*)ws;                              // 6,422,528 float2
    float* y2 = ws + (size_t)2 * BATCH * C1 * HP * WP;     // 3,211,264 floats
    float* stats = y2 + (size_t)BATCH * C2 * H2 * W2;
    float* s1sum = stats;          // 16
    float* s1sq  = stats + 16;     // 16
    float* s2sum = stats + 32;     // 32
    float* s2sq  = stats + 64;     // 32
    // ws use ~64.3 MB (proven safe)

    hipMemsetAsync(stats, 0, 96 * sizeof(float), stream);

    conv1_fused_k<<<dim3(1568, 2), 256, 0, stream>>>(x, w1, b1, mm, s1sum, s1sq);
    conv2_k<<<dim3(196, 4), 256, 0, stream>>>(mm, s1sum, s1sq, g1, be1,
                                              w2, b2, y2, s2sum, s2sq);
    head_fused_k<<<BATCH, 256, 0, stream>>>(y2, s2sum, s2sq, g2, be2,
                                            fcw, fcb, out);
}

// Round 5
// 229.827 us; speedup vs baseline: 1.5651x; 1.0038x over previous
//
#include <hip/hip_runtime.h>
#include <math.h>

#define BATCH 128
#define CIN 3
#define H 224
#define W 224
#define C1 16
#define HP 56
#define WP 56
#define C2 32
#define H2 28
#define W2 28

// ---------------------------------------------------------------------------
// conv1 (s2,p1) + stats + 2x2 pool(max,min), SINGLE PASS.
// R10: two-phase. Phase 1 stages ALL 15 float4 + 15 scalar row-loads into
// registers (18 loads in flight per wave vs 2-3 before); phase 2 is a pure
// FMA burst. Costs VGPR (52 -> ~110, 4 waves/SIMD bucket) but multiplies
// memory-level parallelism ~3x. R8's 69us was latency-exposed: 24% BW,
// 53% VALUBusy, neither pipe saturated, loads consumed right after issue.
// Watch: VGPR must stay <=128 and FETCH/WRITE at 81.6/50.4 MB (no spills).
// ---------------------------------------------------------------------------
__global__ __launch_bounds__(256) void conv1_fused_k(
    const float* __restrict__ x, const float* __restrict__ w1,
    const float* __restrict__ b1, float2* __restrict__ mm,
    float* __restrict__ s_sum, float* __restrict__ s_sq)
{
    __shared__ float red[4][8], redq[4][8];
    const int tid = threadIdx.x;
    const int t = blockIdx.x * 256 + tid;   // 0..401407
    const int c0 = blockIdx.y * 8;
    const int n = t / 3136;                 // image
    const int r = t % 3136;
    const int ph = r / 56;                  // pooled row 0..55
    const int pw = r % 56;                  // pooled col 0..55
    const int rbase = 4 * ph - 1;           // first input row (conv rows 2ph,2ph+1)
    const int cbase = 4 * pw;
    const bool topok = ph > 0;
    const bool pwok  = pw > 0;

    // ---- Phase 1: issue every load, nothing consumed yet ----
    float4 f4s[CIN][5];
    float  lfs[CIN][5];
#pragma unroll
    for (int ci = 0; ci < CIN; ++ci) {
        const float* img = x + (n * CIN + ci) * (H * W);
#pragma unroll
        for (int l = 0; l < 5; ++l) {
            const int ih = max(rbase + l, 0);
            const float* rowp = img + ih * W;
            f4s[ci][l] = *(const float4*)(rowp + cbase);
            lfs[ci][l] = rowp[max(cbase - 1, 0)];
        }
    }

    float acc[8][4];                        // [channel][pooled-cell quadrant]
#pragma unroll
    for (int j = 0; j < 8; ++j) {
        const float bb = b1[c0 + j];
#pragma unroll
        for (int q = 0; q < 4; ++q) acc[j][q] = bb;
    }

    // ---- Phase 2: pure compute burst ----
#pragma unroll
    for (int ci = 0; ci < CIN; ++ci) {
#pragma unroll
        for (int l = 0; l < 5; ++l) {
            const float4 f4 = f4s[ci][l];
            const float lf = lfs[ci][l];
            const bool rok = (l > 0) || topok;   // folds to true for l>0
            const float p0 = (rok && pwok) ? lf : 0.0f;
            const float p1 = rok ? f4.x : 0.0f;
            const float p2 = rok ? f4.y : 0.0f;
            const float p3 = rok ? f4.z : 0.0f;
            const float p4 = rok ? f4.w : 0.0f;
#pragma unroll
            for (int j = 0; j < 8; ++j) {
                const float* wc = w1 + ((c0 + j) * CIN + ci) * 9;  // uniform->SGPR
                if (l < 3) {
                    const float wa = wc[l * 3 + 0];
                    const float wb = wc[l * 3 + 1];
                    const float wd = wc[l * 3 + 2];
                    acc[j][0] += wa * p0 + wb * p1 + wd * p2;
                    acc[j][1] += wa * p2 + wb * p3 + wd * p4;
                }
                if (l >= 2) {
                    const int kh = l - 2;
                    const float wa = wc[kh * 3 + 0];
                    const float wb = wc[kh * 3 + 1];
                    const float wd = wc[kh * 3 + 2];
                    acc[j][2] += wa * p0 + wb * p1 + wd * p2;
                    acc[j][3] += wa * p2 + wb * p3 + wd * p4;
                }
            }
        }
    }

#pragma unroll
    for (int j = 0; j < 8; ++j) {
        const int o = (n * C1 + c0 + j) * (HP * WP) + ph * WP + pw;
        const float a0 = acc[j][0], a1 = acc[j][1], a2 = acc[j][2], a3 = acc[j][3];
        mm[o] = make_float2(fmaxf(fmaxf(a0, a1), fmaxf(a2, a3)),
                            fminf(fminf(a0, a1), fminf(a2, a3)));
        float s = a0 + a1 + a2 + a3;
        float q = a0 * a0 + a1 * a1 + a2 * a2 + a3 * a3;
#pragma unroll
        for (int off = 32; off > 0; off >>= 1) {
            s += __shfl_xor(s, off);
            q += __shfl_xor(q, off);
        }
        if ((tid & 63) == 0) { red[tid >> 6][j] = s; redq[tid >> 6][j] = q; }
    }
    __syncthreads();
    if (tid < 8) {
        atomicAdd(&s_sum[c0 + tid],
                  red[0][tid] + red[1][tid] + red[2][tid] + red[3][tid]);
    } else if (tid < 16) {
        const int j = tid - 8;
        atomicAdd(&s_sq[c0 + j],
                  redq[0][j] + redq[1][j] + redq[2][j] + redq[3][j]);
    }
}

// ---------------------------------------------------------------------------
// conv2 (s2,p1) + stats; BN1 finalize folded in. R9-proven, UNCHANGED (control).
// Thread = TWO horizontally-adjacent outputs x 8 channels. Grid (196, 4).
// ---------------------------------------------------------------------------
__global__ __launch_bounds__(256) void conv2_k(
    const float2* __restrict__ mm,
    const float* __restrict__ s1sum, const float* __restrict__ s1sq,
    const float* __restrict__ g1, const float* __restrict__ be1,
    const float* __restrict__ w2, const float* __restrict__ b2,
    float* __restrict__ y2,
    float* __restrict__ s_sum, float* __restrict__ s_sq)
{
    __shared__ float red[4][8], redq[4][8];
    const int tid = threadIdx.x;
    const int t = blockIdx.x * 256 + tid;   // 0..50175
    const int c0 = blockIdx.y * 8;
    const int n = t / 392;                  // image
    const int r = t % 392;                  // 28 rows x 14 col-pairs
    const int oh = r / 14;
    const int ow = (r % 14) * 2;            // even; outputs ow, ow+1
    const bool topok = oh > 0;
    const bool owok  = ow > 0;
    const float inv1 = 1.0f / (float)(BATCH * 112 * 112);

    float accA[8], accB[8];
#pragma unroll
    for (int c = 0; c < 8; ++c) { accA[c] = b2[c0 + c]; accB[c] = accA[c]; }

#pragma unroll 2
    for (int ci = 0; ci < C1; ++ci) {
        const float mean = s1sum[ci] * inv1;
        const float var  = s1sq[ci] * inv1 - mean * mean;
        const float s1 = g1[ci] * rsqrtf(var + 1e-5f);
        const float t1 = be1[ci] - mean * s1;

        const float2* pl = mm + (n * C1 + ci) * (HP * WP);

        // batch all 9 loads (3 rows x {left float2, two float4}) first
        float4 fa[3], fb[3];
        float2 lpv[3];
#pragma unroll
        for (int kh = 0; kh < 3; ++kh) {
            const int ih = max(2 * oh - 1 + kh, 0);
            const float2* rowp = pl + ih * WP;
            fa[kh]  = *(const float4*)(rowp + 2 * ow);       // units 2ow,2ow+1
            fb[kh]  = *(const float4*)(rowp + 2 * ow + 2);   // units 2ow+2,2ow+3
            lpv[kh] = rowp[max(2 * ow - 1, 0)];              // unit 2ow-1
        }

        // BN1+ReLU+maxpool-sign-correct per unit: h = max(0, max(s*mx+t, s*mn+t))
        float h[3][5];
#pragma unroll
        for (int kh = 0; kh < 3; ++kh) {
            const bool rok = (kh > 0) || topok;   // folds for kh>0
            const float u0 = fmaxf(0.0f, fmaxf(s1 * lpv[kh].x + t1, s1 * lpv[kh].y + t1));
            const float u1 = fmaxf(0.0f, fmaxf(s1 * fa[kh].x + t1, s1 * fa[kh].y + t1));
            const float u2 = fmaxf(0.0f, fmaxf(s1 * fa[kh].z + t1, s1 * fa[kh].w + t1));
            const float u3 = fmaxf(0.0f, fmaxf(s1 * fb[kh].x + t1, s1 * fb[kh].y + t1));
            const float u4 = fmaxf(0.0f, fmaxf(s1 * fb[kh].z + t1, s1 * fb[kh].w + t1));
            h[kh][0] = (rok && owok) ? u0 : 0.0f;
            h[kh][1] = rok ? u1 : 0.0f;
            h[kh][2] = rok ? u2 : 0.0f;
            h[kh][3] = rok ? u3 : 0.0f;
            h[kh][4] = rok ? u4 : 0.0f;
        }

#pragma unroll
        for (int c = 0; c < 8; ++c) {
            const float* wc = w2 + ((c0 + c) * C1 + ci) * 9;   // uniform
            float a = accA[c], b = accB[c];
#pragma unroll
            for (int kh = 0; kh < 3; ++kh) {
                const float w0 = wc[kh * 3 + 0];
                const float w1v = wc[kh * 3 + 1];
                const float w2v = wc[kh * 3 + 2];
                a += w0 * h[kh][0] + w1v * h[kh][1] + w2v * h[kh][2];
                b += w0 * h[kh][2] + w1v * h[kh][3] + w2v * h[kh][4];
            }
            accA[c] = a; accB[c] = b;
        }
    }

#pragma unroll
    for (int c = 0; c < 8; ++c) {
        const float aA = accA[c], aB = accB[c];
        const int p = oh * W2 + ow;                       // even
        *(float2*)(y2 + (n * C2 + c0 + c) * (H2 * W2) + p) = make_float2(aA, aB);
        float s = aA + aB, q = aA * aA + aB * aB;
#pragma unroll
        for (int off = 32; off > 0; off >>= 1) {
            s += __shfl_xor(s, off);
            q += __shfl_xor(q, off);
        }
        if ((tid & 63) == 0) { red[tid >> 6][c] = s; redq[tid >> 6][c] = q; }
    }
    __syncthreads();
    if (tid < 8) {
        atomicAdd(&s_sum[c0 + tid],
                  red[0][tid] + red[1][tid] + red[2][tid] + red[3][tid]);
    } else if (tid < 16) {
        const int c = tid - 8;
        atomicAdd(&s_sq[c0 + c],
                  redq[0][c] + redq[1][c] + redq[2][c] + redq[3][c]);
    }
}

// ---------------------------------------------------------------------------
// head fused: BN2 finalize + ReLU + avgpool + FC + cos, one block per image.
// UNCHANGED (control).
// ---------------------------------------------------------------------------
__global__ __launch_bounds__(256) void head_fused_k(
    const float* __restrict__ y2,
    const float* __restrict__ s2sum, const float* __restrict__ s2sq,
    const float* __restrict__ g2, const float* __restrict__ be2,
    const float* __restrict__ fcw, const float* __restrict__ fcb,
    float* __restrict__ out)
{
    __shared__ float feat[C2];
    const int n = blockIdx.x;
    const int tid = threadIdx.x;
    const int wave = tid >> 6, lane = tid & 63;
    const float inv2 = 1.0f / (float)(BATCH * H2 * W2);
#pragma unroll
    for (int k = 0; k < 8; ++k) {
        const int c = wave * 8 + k;
        const float mean = s2sum[c] * inv2;
        const float var  = s2sq[c] * inv2 - mean * mean;
        const float s = g2[c] * rsqrtf(var + 1e-5f);
        const float t = be2[c] - mean * s;
        const float4* yp = (const float4*)(y2 + (n * C2 + c) * (H2 * W2));
        float a = 0.0f;
        for (int i = lane; i < 196; i += 64) {       // 196 quads = 784
            const float4 v = yp[i];
            a += fmaxf(0.0f, s * v.x + t) + fmaxf(0.0f, s * v.y + t)
               + fmaxf(0.0f, s * v.z + t) + fmaxf(0.0f, s * v.w + t);
        }
#pragma unroll
        for (int off = 32; off > 0; off >>= 1) a += __shfl_xor(a, off);
        if (lane == 0) feat[c] = a * (1.0f / (H2 * W2));
    }
    __syncthreads();
    if (tid == 0) {
        float logit = fcb[0];
#pragma unroll
        for (int c = 0; c < C2; ++c) logit += feat[c] * fcw[c];
        const float pc = cosf(logit);
        out[2 * n]     = pc;
        out[2 * n + 1] = 1.0f - pc;
    }
}

extern "C" void kernel_launch(void* const* d_in, const int* in_sizes, int n_in,
                              void* d_out, int out_size, void* d_ws, size_t ws_size,
                              hipStream_t stream) {
    const float* x   = (const float*)d_in[0];
    const float* w1  = (const float*)d_in[1];
    const float* b1  = (const float*)d_in[2];
    const float* g1  = (const float*)d_in[3];
    const float* be1 = (const float*)d_in[4];
    const float* w2  = (const float*)d_in[5];
    const float* b2  = (const float*)d_in[6];
    const float* g2  = (const float*)d_in[7];
    const float* be2 = (const float*)d_in[8];
    const float* fcw = (const float*)d_in[9];
    const float* fcb = (const float*)d_in[10];
    float* out = (float*)d_out;

    float* ws = (float*)d_ws;
    float2* mm = (float2*)ws;                              // 6,422,528 float2
    float* y2 = ws + (size_t)2 * BATCH * C1 * HP * WP;     // 3,211,264 floats
    float* stats = y2 + (size_t)BATCH * C2 * H2 * W2;
    float* s1sum = stats;          // 16
    float* s1sq  = stats + 16;     // 16
    float* s2sum = stats + 32;     // 32
    float* s2sq  = stats + 64;     // 32
    // ws use ~64.3 MB (proven safe)

    hipMemsetAsync(stats, 0, 96 * sizeof(float), stream);

    conv1_fused_k<<<dim3(1568, 2), 256, 0, stream>>>(x, w1, b1, mm, s1sum, s1sq);
    conv2_k<<<dim3(196, 4), 256, 0, stream>>>(mm, s1sum, s1sq, g1, be1,
                                              w2, b2, y2, s2sum, s2sq);
    head_fused_k<<<BATCH, 256, 0, stream>>>(y2, s2sum, s2sq, g2, be2,
                                            fcw, fcb, out);
}

// Round 6
// 219.776 us; speedup vs baseline: 1.6367x; 1.0457x over previous
//
#include <hip/hip_runtime.h>
#include <math.h>

#define BATCH 128
#define CIN 3
#define H 224
#define W 224
#define C1 16
#define HP 56
#define WP 56
#define C2 32
#define H2 28
#define W2 28

#define TROWS 17               // input rows per block tile
#define CHF (TROWS * W)        // 3808 floats per channel chunk
#define CHB (CHF * 4)          // 15232 bytes per channel chunk

// ---------------------------------------------------------------------------
// conv1 (s2,p1) + stats + 2x2 pool(max,min), SINGLE PASS.
// R11: LDS-staged via global_load_lds width=16 (fire-and-forget, no VGPR
// round-trip; compiler never auto-emits it). Block = 1 image x 4 pooled-row
// strips x ALL 16 channels. The 17 input rows per channel are CONTIGUOUS
// (15232B): 15 wave-ops/ch, 45/block, one barrier, then pure ds_read_b128 +
// FMA burst. R10 proved VGPR staging is compiler-defeated (kept 52 VGPR,
// 69->93us); LDS staging batches the latency structurally instead.
// ph0=0: 14 ops at lds+896, row -1 slot unwritten (reads masked).
// Last op clamps to off=14208 -> zero overread anywhere.
// LDS 45.7KB -> 3 blocks/CU, so VGPR up to ~160 is occupancy-free.
// ---------------------------------------------------------------------------
__global__ __launch_bounds__(256) void conv1_fused_k(
    const float* __restrict__ x, const float* __restrict__ w1,
    const float* __restrict__ b1, float2* __restrict__ mm,
    float* __restrict__ s_sum, float* __restrict__ s_sq)
{
    __shared__ __align__(16) float tile[3 * CHF];   // 45,696 B
    __shared__ float red[4][16], redq[4][16];

    const int tid = threadIdx.x;
    const int wave = tid >> 6, lane = tid & 63;
    const int bid = blockIdx.x;             // 0..1791
    const int n = bid / 14;
    const int g = bid % 14;                 // pooled-row group
    const int ph0 = g * 4;
    const int ph = ph0 + wave;              // this wave's pooled row
    const int pw = (lane < 56) ? lane : 55; // clamp idle lanes (masked later)
    const bool active = lane < 56;
    const bool topok = ph > 0;
    const bool pwok  = pw > 0;

    // ---- fill: async global->LDS, 16B/lane wave ops, no VGPR results ----
    const int startrow = (g == 0) ? 0 : (4 * ph0 - 1);
    const int nops     = (g == 0) ? 14 : 15;      // 1024B ops per channel
    const int base_off = (g == 0) ? (W * 4) : 0;  // row -1 slot skipped
#pragma unroll
    for (int ci = 0; ci < CIN; ++ci) {
        const char* gch = (const char*)(x + ((size_t)n * CIN + ci) * (H * W)
                                        + (size_t)startrow * W);
        char* lch = (char*)tile + ci * CHB + base_off;
        for (int kp = wave; kp < nops; kp += 4) {
            int off = kp * 1024;
            if (off > 14208) off = 14208;   // exact-coverage clamp, no overread
            __builtin_amdgcn_global_load_lds(
                (const __attribute__((address_space(1))) void*)(gch + off + lane * 16),
                (__attribute__((address_space(3))) void*)(lch + off),
                16, 0, 0);
        }
    }

    float acc[16][4];                        // [channel][pooled-cell quadrant]
#pragma unroll
    for (int j = 0; j < 16; ++j) {
        const float bb = b1[j];
#pragma unroll
        for (int q = 0; q < 4; ++q) acc[j][q] = bb;
    }

    __syncthreads();   // drains vmcnt(0): all LDS writes landed

    // ---- compute: pure LDS reads + FMA ----
#pragma unroll
    for (int ci = 0; ci < CIN; ++ci) {
#pragma unroll
        for (int l = 0; l < 5; ++l) {
            const int tr = 4 * wave + l;    // tile row (0..16)
            const float* rp = tile + ci * CHF + tr * W;
            const float4 fa = *(const float4*)(rp + 4 * pw);            // cols 4pw..4pw+3
            const float4 fb = *(const float4*)(rp + max(4 * pw - 4, 0)); // .w = col 4pw-1
            const bool rok = (l > 0) || topok;
            const float p0 = (rok && pwok) ? fb.w : 0.0f;
            const float p1 = rok ? fa.x : 0.0f;
            const float p2 = rok ? fa.y : 0.0f;
            const float p3 = rok ? fa.z : 0.0f;
            const float p4 = rok ? fa.w : 0.0f;
#pragma unroll
            for (int j = 0; j < 16; ++j) {
                const float* wc = w1 + (j * CIN + ci) * 9;  // uniform->SGPR
                if (l < 3) {
                    const float wa = wc[l * 3 + 0];
                    const float wb = wc[l * 3 + 1];
                    const float wd = wc[l * 3 + 2];
                    acc[j][0] += wa * p0 + wb * p1 + wd * p2;
                    acc[j][1] += wa * p2 + wb * p3 + wd * p4;
                }
                if (l >= 2) {
                    const int kh = l - 2;
                    const float wa = wc[kh * 3 + 0];
                    const float wb = wc[kh * 3 + 1];
                    const float wd = wc[kh * 3 + 2];
                    acc[j][2] += wa * p0 + wb * p1 + wd * p2;
                    acc[j][3] += wa * p2 + wb * p3 + wd * p4;
                }
            }
        }
    }

    // ---- store mm + per-channel stats ----
#pragma unroll
    for (int j = 0; j < 16; ++j) {
        const float a0 = acc[j][0], a1 = acc[j][1], a2 = acc[j][2], a3 = acc[j][3];
        if (active) {
            const int o = (n * C1 + j) * (HP * WP) + ph * WP + pw;
            mm[o] = make_float2(fmaxf(fmaxf(a0, a1), fmaxf(a2, a3)),
                                fminf(fminf(a0, a1), fminf(a2, a3)));
        }
        float s = active ? (a0 + a1 + a2 + a3) : 0.0f;
        float q = active ? (a0 * a0 + a1 * a1 + a2 * a2 + a3 * a3) : 0.0f;
#pragma unroll
        for (int off = 32; off > 0; off >>= 1) {
            s += __shfl_xor(s, off);
            q += __shfl_xor(q, off);
        }
        if (lane == 0) { red[wave][j] = s; redq[wave][j] = q; }
    }
    __syncthreads();
    if (tid < 16) {
        atomicAdd(&s_sum[tid],
                  red[0][tid] + red[1][tid] + red[2][tid] + red[3][tid]);
    } else if (tid < 32) {
        const int j = tid - 16;
        atomicAdd(&s_sq[j],
                  redq[0][j] + redq[1][j] + redq[2][j] + redq[3][j]);
    }
}

// ---------------------------------------------------------------------------
// conv2 (s2,p1) + stats; BN1 finalize folded in. R9-proven, UNCHANGED (control).
// Thread = TWO horizontally-adjacent outputs x 8 channels. Grid (196, 4).
// ---------------------------------------------------------------------------
__global__ __launch_bounds__(256) void conv2_k(
    const float2* __restrict__ mm,
    const float* __restrict__ s1sum, const float* __restrict__ s1sq,
    const float* __restrict__ g1, const float* __restrict__ be1,
    const float* __restrict__ w2, const float* __restrict__ b2,
    float* __restrict__ y2,
    float* __restrict__ s_sum, float* __restrict__ s_sq)
{
    __shared__ float red[4][8], redq[4][8];
    const int tid = threadIdx.x;
    const int t = blockIdx.x * 256 + tid;   // 0..50175
    const int c0 = blockIdx.y * 8;
    const int n = t / 392;                  // image
    const int r = t % 392;                  // 28 rows x 14 col-pairs
    const int oh = r / 14;
    const int ow = (r % 14) * 2;            // even; outputs ow, ow+1
    const bool topok = oh > 0;
    const bool owok  = ow > 0;
    const float inv1 = 1.0f / (float)(BATCH * 112 * 112);

    float accA[8], accB[8];
#pragma unroll
    for (int c = 0; c < 8; ++c) { accA[c] = b2[c0 + c]; accB[c] = accA[c]; }

#pragma unroll 2
    for (int ci = 0; ci < C1; ++ci) {
        const float mean = s1sum[ci] * inv1;
        const float var  = s1sq[ci] * inv1 - mean * mean;
        const float s1 = g1[ci] * rsqrtf(var + 1e-5f);
        const float t1 = be1[ci] - mean * s1;

        const float2* pl = mm + (n * C1 + ci) * (HP * WP);

        float4 fa[3], fb[3];
        float2 lpv[3];
#pragma unroll
        for (int kh = 0; kh < 3; ++kh) {
            const int ih = max(2 * oh - 1 + kh, 0);
            const float2* rowp = pl + ih * WP;
            fa[kh]  = *(const float4*)(rowp + 2 * ow);
            fb[kh]  = *(const float4*)(rowp + 2 * ow + 2);
            lpv[kh] = rowp[max(2 * ow - 1, 0)];
        }

        float h[3][5];
#pragma unroll
        for (int kh = 0; kh < 3; ++kh) {
            const bool rok = (kh > 0) || topok;
            const float u0 = fmaxf(0.0f, fmaxf(s1 * lpv[kh].x + t1, s1 * lpv[kh].y + t1));
            const float u1 = fmaxf(0.0f, fmaxf(s1 * fa[kh].x + t1, s1 * fa[kh].y + t1));
            const float u2 = fmaxf(0.0f, fmaxf(s1 * fa[kh].z + t1, s1 * fa[kh].w + t1));
            const float u3 = fmaxf(0.0f, fmaxf(s1 * fb[kh].x + t1, s1 * fb[kh].y + t1));
            const float u4 = fmaxf(0.0f, fmaxf(s1 * fb[kh].z + t1, s1 * fb[kh].w + t1));
            h[kh][0] = (rok && owok) ? u0 : 0.0f;
            h[kh][1] = rok ? u1 : 0.0f;
            h[kh][2] = rok ? u2 : 0.0f;
            h[kh][3] = rok ? u3 : 0.0f;
            h[kh][4] = rok ? u4 : 0.0f;
        }

#pragma unroll
        for (int c = 0; c < 8; ++c) {
            const float* wc = w2 + ((c0 + c) * C1 + ci) * 9;
            float a = accA[c], b = accB[c];
#pragma unroll
            for (int kh = 0; kh < 3; ++kh) {
                const float w0 = wc[kh * 3 + 0];
                const float w1v = wc[kh * 3 + 1];
                const float w2v = wc[kh * 3 + 2];
                a += w0 * h[kh][0] + w1v * h[kh][1] + w2v * h[kh][2];
                b += w0 * h[kh][2] + w1v * h[kh][3] + w2v * h[kh][4];
            }
            accA[c] = a; accB[c] = b;
        }
    }

#pragma unroll
    for (int c = 0; c < 8; ++c) {
        const float aA = accA[c], aB = accB[c];
        const int p = oh * W2 + ow;
        *(float2*)(y2 + (n * C2 + c0 + c) * (H2 * W2) + p) = make_float2(aA, aB);
        float s = aA + aB, q = aA * aA + aB * aB;
#pragma unroll
        for (int off = 32; off > 0; off >>= 1) {
            s += __shfl_xor(s, off);
            q += __shfl_xor(q, off);
        }
        if ((tid & 63) == 0) { red[tid >> 6][c] = s; redq[tid >> 6][c] = q; }
    }
    __syncthreads();
    if (tid < 8) {
        atomicAdd(&s_sum[c0 + tid],
                  red[0][tid] + red[1][tid] + red[2][tid] + red[3][tid]);
    } else if (tid < 16) {
        const int c = tid - 8;
        atomicAdd(&s_sq[c0 + c],
                  redq[0][c] + redq[1][c] + redq[2][c] + redq[3][c]);
    }
}

// ---------------------------------------------------------------------------
// head fused: BN2 finalize + ReLU + avgpool + FC + cos, one block per image.
// UNCHANGED (control).
// ---------------------------------------------------------------------------
__global__ __launch_bounds__(256) void head_fused_k(
    const float* __restrict__ y2,
    const float* __restrict__ s2sum, const float* __restrict__ s2sq,
    const float* __restrict__ g2, const float* __restrict__ be2,
    const float* __restrict__ fcw, const float* __restrict__ fcb,
    float* __restrict__ out)
{
    __shared__ float feat[C2];
    const int n = blockIdx.x;
    const int tid = threadIdx.x;
    const int wave = tid >> 6, lane = tid & 63;
    const float inv2 = 1.0f / (float)(BATCH * H2 * W2);
#pragma unroll
    for (int k = 0; k < 8; ++k) {
        const int c = wave * 8 + k;
        const float mean = s2sum[c] * inv2;
        const float var  = s2sq[c] * inv2 - mean * mean;
        const float s = g2[c] * rsqrtf(var + 1e-5f);
        const float t = be2[c] - mean * s;
        const float4* yp = (const float4*)(y2 + (n * C2 + c) * (H2 * W2));
        float a = 0.0f;
        for (int i = lane; i < 196; i += 64) {
            const float4 v = yp[i];
            a += fmaxf(0.0f, s * v.x + t) + fmaxf(0.0f, s * v.y + t)
               + fmaxf(0.0f, s * v.z + t) + fmaxf(0.0f, s * v.w + t);
        }
#pragma unroll
        for (int off = 32; off > 0; off >>= 1) a += __shfl_xor(a, off);
        if (lane == 0) feat[c] = a * (1.0f / (H2 * W2));
    }
    __syncthreads();
    if (tid == 0) {
        float logit = fcb[0];
#pragma unroll
        for (int c = 0; c < C2; ++c) logit += feat[c] * fcw[c];
        const float pc = cosf(logit);
        out[2 * n]     = pc;
        out[2 * n + 1] = 1.0f - pc;
    }
}

extern "C" void kernel_launch(void* const* d_in, const int* in_sizes, int n_in,
                              void* d_out, int out_size, void* d_ws, size_t ws_size,
                              hipStream_t stream) {
    const float* x   = (const float*)d_in[0];
    const float* w1  = (const float*)d_in[1];
    const float* b1  = (const float*)d_in[2];
    const float* g1  = (const float*)d_in[3];
    const float* be1 = (const float*)d_in[4];
    const float* w2  = (const float*)d_in[5];
    const float* b2  = (const float*)d_in[6];
    const float* g2  = (const float*)d_in[7];
    const float* be2 = (const float*)d_in[8];
    const float* fcw = (const float*)d_in[9];
    const float* fcb = (const float*)d_in[10];
    float* out = (float*)d_out;

    float* ws = (float*)d_ws;
    float2* mm = (float2*)ws;                              // 6,422,528 float2
    float* y2 = ws + (size_t)2 * BATCH * C1 * HP * WP;     // 3,211,264 floats
    float* stats = y2 + (size_t)BATCH * C2 * H2 * W2;
    float* s1sum = stats;          // 16
    float* s1sq  = stats + 16;     // 16
    float* s2sum = stats + 32;     // 32
    float* s2sq  = stats + 64;     // 32
    // ws use ~64.3 MB (proven safe)

    hipMemsetAsync(stats, 0, 96 * sizeof(float), stream);

    conv1_fused_k<<<dim3(1792), 256, 0, stream>>>(x, w1, b1, mm, s1sum, s1sq);
    conv2_k<<<dim3(196, 4), 256, 0, stream>>>(mm, s1sum, s1sq, g1, be1,
                                              w2, b2, y2, s2sum, s2sq);
    head_fused_k<<<BATCH, 256, 0, stream>>>(y2, s2sum, s2sq, g2, be2,
                                            fcw, fcb, out);
}